// Round 14
// baseline (8944.487 us; speedup 1.0000x reference)
//
#include <hip/hip_runtime.h>

typedef __attribute__((ext_vector_type(8))) short bf16x8;
typedef __attribute__((ext_vector_type(4))) float f32x4;
typedef __attribute__((ext_vector_type(2))) unsigned int uint2v;

union FU { unsigned int u[4]; uint4 q; bf16x8 v; };

__device__ inline unsigned int cvt_pk(float lo, float hi) {
    unsigned int r;
    asm("v_cvt_pk_bf16_f32 %0, %1, %2" : "=v"(r) : "v"(lo), "v"(hi));
    return r;
}

// tanh(x) = 1 - 2/(2^(x*2log2e)+1). Native exp2 builtin (R10-proven).
#define TWO_LOG2E 2.8853900817779268f
__device__ inline float tanh_fast(float x) {
#if __has_builtin(__builtin_amdgcn_exp2f)
    float e = __builtin_amdgcn_exp2f(x * TWO_LOG2E);
#else
    float e = __expf(x + x);
#endif
    return fmaf(-2.f, __builtin_amdgcn_rcpf(e + 1.f), 1.f);
}

// lane l + lane l^32 on VALU (R5-proven asm).
__device__ inline float xor32_add(float p) {
    float c = p;
    asm("v_permlane32_swap_b32 %0, %1" : "+v"(c), "+v"(p));
    return p + c;
}

// lane l + lane l^16 via compiler-modeled builtin (R13-proven bit-exact).
__device__ inline float xor16_add(float p) {
#if __has_builtin(__builtin_amdgcn_permlane16_swap)
    uint2v r = __builtin_amdgcn_permlane16_swap(__float_as_uint(p),
                                                __float_as_uint(p),
                                                false, false);
    return __uint_as_float(r[0]) + __uint_as_float(r[1]);
#else
    return p + __shfl_xor(p, 16);
#endif
}

// Barrier waiting only on LDS ops (R9/R10-proven >= neutral).
__device__ inline void lds_barrier() {
    asm volatile("s_waitcnt lgkmcnt(0)\n\ts_barrier" ::: "memory");
}

#define TS 1000
#define NEV ((TS - 1) * 4)
#define ROWU 33            // uint4 granules per h1 row (512B + 16B pad)
#define P2ROW 208          // part2 row bytes: 8x16 hi quads + 8x8 lo pairs + pad

// R14: two-stream software pipeline. Block owns 32 batch rows = 2 streams x 16.
// Slot even(ev): B(s0,ev) || [combine+advance(s1,ev-1); A(s1,ev)]   | barrier
// Slot odd (ev): B(s1,ev) || [combine+advance(s0,ev);  A(s0,ev+1)]  | barrier
// -> 1 barrier per eval (was 2), and every interval has independent A||B work.
// Weights shared across streams. Grid 256 -> 1 block/CU; launch_bounds(512,2)
// lifts the 128-reg cliff (only 8 waves/CU needed by construction).
__global__ __launch_bounds__(512, 2)
void node_ode_kernel(const float* __restrict__ Ig, const float* __restrict__ tg,
                     const float* __restrict__ W1g, const float* __restrict__ b1g,
                     const float* __restrict__ W2g, const float* __restrict__ b2g,
                     const float* __restrict__ W3g, const float* __restrict__ b3g,
                     float* __restrict__ outp)
{
    __shared__ __align__(16) uint4 h1q[2][16 * ROWU];    // 2 x 8448 B
    __shared__ __align__(16) char part2[2][16 * P2ROW];  // 2 x 3328 B
    __shared__ float dtss[TS - 1];                       // 3996 B

    const int tid  = threadIdx.x;
    const int lane = tid & 63;
    const int wv   = tid >> 6;       // 0..7
    const int nb   = lane & 15;      // batch row within stream
    const int g4   = lane >> 4;      // 0..3
    const int bb0  = blockIdx.x * 32;

    const int wslot = nb * ROWU + wv * 4 + g4;   // stage-A write slot (uint4)
    const int rslot = nb * ROWU + g4;            // stage-B read base (+ks*4)
    char* const prow0 = part2[0] + nb * P2ROW;
    char* const prow1 = part2[1] + nb * P2ROW;

    for (int i = tid; i < TS - 1; i += 512) dtss[i] = tg[i + 1] - tg[i];

    const float b30 = b3g[0], b31 = b3g[1], b32 = b3g[2];
    float4 b2r0 = *(const float4*)&b2g[wv * 32 + g4 * 4];
    float4 b2r1 = *(const float4*)&b2g[wv * 32 + 16 + g4 * 4];

    // ---- per-stream RK4 state (redundant across the 32 threads sharing nb) ----
    float y0_0 = Ig[(bb0 + nb) * 3 + 0];
    float y0_1 = Ig[(bb0 + nb) * 3 + 1];
    float y0_2 = Ig[(bb0 + nb) * 3 + 2];
    float y1_0 = Ig[(bb0 + 16 + nb) * 3 + 0];
    float y1_1 = Ig[(bb0 + 16 + nb) * 3 + 1];
    float y1_2 = Ig[(bb0 + 16 + nb) * 3 + 2];
    float yc0_0 = y0_0, yc0_1 = y0_1, yc0_2 = y0_2;
    float yc1_0 = y1_0, yc1_1 = y1_1, yc1_2 = y1_2;
    float ks0_0 = 0.f, ks0_1 = 0.f, ks0_2 = 0.f;
    float ks1_0 = 0.f, ks1_1 = 0.f, ks1_2 = 0.f;
    if (tid < 32) {
        size_t o = (size_t)(bb0 + tid) * (TS * 3);
        float a0 = Ig[(bb0 + tid) * 3 + 0];
        float a1 = Ig[(bb0 + tid) * 3 + 1];
        float a2 = Ig[(bb0 + tid) * 3 + 2];
        outp[o + 0] = a0; outp[o + 1] = a1; outp[o + 2] = a2;
    }

    // ---- W2 persistent A-frags (unpermuted cols, R8 VERBATIM; shared) ----
    bf16x8 w2f[2][8];
    {
        const int ncb = wv * 32 + nb;
        #pragma unroll
        for (int mt = 0; mt < 2; ++mt) {
            #pragma unroll
            for (int ks = 0; ks < 8; ++ks) {
                FU f;
                #pragma unroll
                for (int jj = 0; jj < 4; ++jj) {
                    int k0 = ks * 32 + g4 * 8 + jj * 2;
                    f.u[jj] = cvt_pk(W2g[(size_t)k0 * 256 + ncb + mt * 16],
                                     W2g[(size_t)(k0 + 1) * 256 + ncb + mt * 16]);
                }
                w2f[mt][ks] = f.v;
            }
        }
    }

    // ---- W1 persistent A-frags (permuted cols, split precision; shared) ----
    bf16x8 w1a[2];
    {
        const int colb = wv * 32 + ((nb >> 2) << 3) + (nb & 3);
        #pragma unroll
        for (int mt = 0; mt < 2; ++mt) {
            const int col = colb + mt * 4;
            float w0 = W1g[col], w1 = W1g[256 + col], w2 = W1g[512 + col];
            float bb = b1g[col];
            FU f;
            if (g4 == 0) {
                f.u[0] = cvt_pk(w0, w1);
                f.u[1] = cvt_pk(w2, w0);
                f.u[2] = cvt_pk(w1, w2);
                f.u[3] = cvt_pk(bb, 0.f);
            } else if (g4 == 1) {
                unsigned int p01 = cvt_pk(w0, w1);
                unsigned int p2x = cvt_pk(w2, 0.f);
                float w0l = w0 - __uint_as_float(p01 << 16);
                float w1l = w1 - __uint_as_float(p01 & 0xFFFF0000u);
                float w2l = w2 - __uint_as_float(p2x << 16);
                f.u[0] = cvt_pk(w0l, w1l);
                f.u[1] = cvt_pk(w2l, 0.f);
                f.u[2] = 0u; f.u[3] = 0u;
            } else {
                f.u[0] = f.u[1] = f.u[2] = f.u[3] = 0u;
            }
            w1a[mt] = f.v;
        }
    }

    // ---- W3 persistent A-frag (rows 0-2 hi, 3-5 lo; shared) ----
    bf16x8 w3a;
    {
        FU f; f.u[0] = f.u[1] = f.u[2] = f.u[3] = 0u;
        if (nb < 6) {
            const int d = (nb < 3) ? nb : nb - 3;
            float w[8];
            #pragma unroll
            for (int j = 0; j < 8; ++j) {
                int ch = (j < 4) ? (wv * 32 + 4 * g4 + j)
                                 : (wv * 32 + 16 + 4 * g4 + (j - 4));
                w[j] = W3g[ch * 3 + d];
            }
            #pragma unroll
            for (int p = 0; p < 4; ++p) {
                unsigned int hp = cvt_pk(w[2 * p], w[2 * p + 1]);
                if (nb < 3) {
                    f.u[p] = hp;
                } else {
                    float l0 = w[2 * p]     - __uint_as_float(hp << 16);
                    float l1 = w[2 * p + 1] - __uint_as_float(hp & 0xFFFF0000u);
                    f.u[p] = cvt_pk(l0, l1);
                }
            }
        }
        w3a = f.v;
    }
    __syncthreads();   // init barrier: full drain, once

    // ---- stage bodies (R13 verbatim, parametrized by stream buffers) ----
    auto stageA = [&](float ycx, float ycy, float ycz, uint4* hb) {
        unsigned int u01  = cvt_pk(ycx, ycy);
        float yl0 = ycx - __uint_as_float(u01 << 16);
        float yl1 = ycy - __uint_as_float(u01 & 0xFFFF0000u);
        unsigned int u2l0 = cvt_pk(ycz, yl0);
        float yl2 = ycz - __uint_as_float(u2l0 << 16);
        unsigned int ull  = cvt_pk(yl1, yl2);
        FU bf;
        if (g4 == 0) {
            bf.u[0] = u01; bf.u[1] = u2l0; bf.u[2] = ull; bf.u[3] = 0x00003f80u;
        } else if (g4 == 1) {
            bf.u[0] = u01; bf.u[1] = u2l0 & 0x0000FFFFu; bf.u[2] = 0u; bf.u[3] = 0u;
        } else {
            bf.u[0] = bf.u[1] = bf.u[2] = bf.u[3] = 0u;
        }
        f32x4 dA = {0.f, 0.f, 0.f, 0.f};
        f32x4 dB = {0.f, 0.f, 0.f, 0.f};
        dA = __builtin_amdgcn_mfma_f32_16x16x32_bf16(w1a[0], bf.v, dA, 0, 0, 0);
        dB = __builtin_amdgcn_mfma_f32_16x16x32_bf16(w1a[1], bf.v, dB, 0, 0, 0);
        uint4 wq;
        wq.x = cvt_pk(tanh_fast(dA[0]), tanh_fast(dA[1]));
        wq.y = cvt_pk(tanh_fast(dA[2]), tanh_fast(dA[3]));
        wq.z = cvt_pk(tanh_fast(dB[0]), tanh_fast(dB[1]));
        wq.w = cvt_pk(tanh_fast(dB[2]), tanh_fast(dB[3]));
        hb[wslot] = wq;
    };

    auto stageB = [&](const uint4* hb, char* pw) {
        f32x4 acc0 = {b2r0.x, b2r0.y, b2r0.z, b2r0.w};
        f32x4 acc1 = {b2r1.x, b2r1.y, b2r1.z, b2r1.w};
        #pragma unroll
        for (int ks = 0; ks < 8; ++ks) {
            FU tm; tm.q = hb[rslot + ks * 4];
            acc0 = __builtin_amdgcn_mfma_f32_16x16x32_bf16(w2f[0][ks], tm.v, acc0, 0, 0, 0);
            acc1 = __builtin_amdgcn_mfma_f32_16x16x32_bf16(w2f[1][ks], tm.v, acc1, 0, 0, 0);
        }
        FU pb;
        pb.u[0] = cvt_pk(tanh_fast(acc0[0]), tanh_fast(acc0[1]));
        pb.u[1] = cvt_pk(tanh_fast(acc0[2]), tanh_fast(acc0[3]));
        pb.u[2] = cvt_pk(tanh_fast(acc1[0]), tanh_fast(acc1[1]));
        pb.u[3] = cvt_pk(tanh_fast(acc1[2]), tanh_fast(acc1[3]));
        f32x4 pd = {0.f, 0.f, 0.f, 0.f};
        pd = __builtin_amdgcn_mfma_f32_16x16x32_bf16(w3a, pb.v, pd, 0, 0, 0);
        if (g4 == 0)
            *(float4*)(pw + wv * 16) = make_float4(pd[0], pd[1], pd[2], pd[3]);
        else if (g4 == 1)
            *(float2*)(pw + 128 + wv * 8) = make_float2(pd[0], pd[1]);
    };

    auto combine = [&](const char* pr, float& kkx, float& kky, float& kkz) {
        float4 q1 = *(const float4*)(pr + g4 * 16);
        float4 q2 = *(const float4*)(pr + 64 + g4 * 16);
        float4 q3 = *(const float4*)(pr + 128 + g4 * 16);
        float k0 = (q1.x + q2.x) + (q1.w + q2.w);
        float k1 = (q1.y + q2.y) + (q3.x + q3.z);
        float k2 = (q1.z + q2.z) + (q3.y + q3.w);
        k0 = xor16_add(k0); k1 = xor16_add(k1); k2 = xor16_add(k2);
        kkx = xor32_add(k0) + b30;
        kky = xor32_add(k1) + b31;
        kkz = xor32_add(k2) + b32;
    };

    // RK4 state machine: combine of eval ev (pph = ev&3) advances one stream.
    auto advance = [&](int ev, float k0, float k1, float k2,
                       float& y0, float& y1, float& y2,
                       float& ks0, float& ks1, float& ks2,
                       float& yc0, float& yc1, float& yc2, int rowoff) {
        const int pph = ev & 3;
        const int t = ev >> 2;
        float dtc = dtss[t];
        if (pph == 0) {
            ks0 = k0; ks1 = k1; ks2 = k2;
            float h = 0.5f * dtc;
            yc0 = fmaf(h, k0, y0); yc1 = fmaf(h, k1, y1); yc2 = fmaf(h, k2, y2);
        } else if (pph == 1) {
            ks0 += 2.f * k0; ks1 += 2.f * k1; ks2 += 2.f * k2;
            float h = 0.5f * dtc;
            yc0 = fmaf(h, k0, y0); yc1 = fmaf(h, k1, y1); yc2 = fmaf(h, k2, y2);
        } else if (pph == 2) {
            ks0 += 2.f * k0; ks1 += 2.f * k1; ks2 += 2.f * k2;
            yc0 = fmaf(dtc, k0, y0); yc1 = fmaf(dtc, k1, y1); yc2 = fmaf(dtc, k2, y2);
        } else {
            float s = dtc * (1.f / 6.f);
            y0 = fmaf(s, ks0 + k0, y0);
            y1 = fmaf(s, ks1 + k1, y1);
            y2 = fmaf(s, ks2 + k2, y2);
            yc0 = y0; yc1 = y1; yc2 = y2;
            if ((wv == (t & 7)) && lane < 16) {
                size_t o = (size_t)(bb0 + rowoff + nb) * (TS * 3) + (size_t)(t + 1) * 3;
                outp[o + 0] = y0; outp[o + 1] = y1; outp[o + 2] = y2;
            }
        }
    };

    // ---- pipeline ----
    stageA(yc0_0, yc0_1, yc0_2, h1q[0]);     // prologue: A(s0, ev0)
    lds_barrier();
    for (int ev = 0; ev < NEV; ++ev) {
        // even slot: B(s0,ev) || combine+advance(s1,ev-1) -> A(s1,ev)
        stageB(h1q[0], prow0);
        if (ev > 0) {
            float k0, k1, k2;
            combine(prow1, k0, k1, k2);
            advance(ev - 1, k0, k1, k2, y1_0, y1_1, y1_2,
                    ks1_0, ks1_1, ks1_2, yc1_0, yc1_1, yc1_2, 16);
        }
        stageA(yc1_0, yc1_1, yc1_2, h1q[1]);
        lds_barrier();
        // odd slot: B(s1,ev) || combine+advance(s0,ev) -> A(s0,ev+1)
        stageB(h1q[1], prow1);
        {
            float k0, k1, k2;
            combine(prow0, k0, k1, k2);
            advance(ev, k0, k1, k2, y0_0, y0_1, y0_2,
                    ks0_0, ks0_1, ks0_2, yc0_0, yc0_1, yc0_2, 0);
        }
        if (ev < NEV - 1) stageA(yc0_0, yc0_1, yc0_2, h1q[0]);
        lds_barrier();
    }
    // tail: final combine for s1
    {
        float k0, k1, k2;
        combine(prow1, k0, k1, k2);
        advance(NEV - 1, k0, k1, k2, y1_0, y1_1, y1_2,
                ks1_0, ks1_1, ks1_2, yc1_0, yc1_1, yc1_2, 16);
    }
}

extern "C" void kernel_launch(void* const* d_in, const int* in_sizes, int n_in,
                              void* d_out, int out_size, void* d_ws, size_t ws_size,
                              hipStream_t stream) {
    (void)in_sizes; (void)n_in; (void)d_ws; (void)ws_size; (void)out_size;
    const float* Ig  = (const float*)d_in[0];
    const float* tg  = (const float*)d_in[1];
    const float* W1g = (const float*)d_in[2];
    const float* b1g = (const float*)d_in[3];
    const float* W2g = (const float*)d_in[4];
    const float* b2g = (const float*)d_in[5];
    const float* W3g = (const float*)d_in[6];
    const float* b3g = (const float*)d_in[7];
    float* outp = (float*)d_out;

    dim3 grid(256), block(512);
    hipLaunchKernelGGL(node_ode_kernel, grid, block, 0, stream,
                       Ig, tg, W1g, b1g, W2g, b2g, W3g, b3g, outp);
}

// Round 15
// 6739.737 us; speedup vs baseline: 1.3271x; 1.3271x over previous
//
#include <hip/hip_runtime.h>

typedef __attribute__((ext_vector_type(8))) short bf16x8;
typedef __attribute__((ext_vector_type(4))) float f32x4;
typedef __attribute__((ext_vector_type(2))) unsigned int uint2v;

union FU { unsigned int u[4]; uint4 q; bf16x8 v; };

__device__ inline unsigned int cvt_pk(float lo, float hi) {
    unsigned int r;
    asm("v_cvt_pk_bf16_f32 %0, %1, %2" : "=v"(r) : "v"(lo), "v"(hi));
    return r;
}

// Scale S = 2*log2(e) is folded into W1(split, exact), b1, b2, and the h1
// bf16 values (stored as S*tanh). Every tanh then takes a PRE-SCALED input d:
//   tanh = 1 - 2/(2^d + 1)   (no per-tanh input mul).
#define SCL  2.8853900817779268f
#define N2S (-5.7707801635558537f)   // -2*SCL
__device__ inline float exp2_nat(float x) {
#if __has_builtin(__builtin_amdgcn_exp2f)
    return __builtin_amdgcn_exp2f(x);
#else
    return __expf(x * 0.6931471805599453f);
#endif
}
// unscaled tanh from pre-scaled input (stage B, feeds W3)
__device__ inline float tanh_pre(float d) {
    return fmaf(-2.f, __builtin_amdgcn_rcpf(exp2_nat(d) + 1.f), 1.f);
}
// S*tanh from pre-scaled input (stage A, feeds W2 whose inputs carry the scale)
__device__ inline float tanh_pre_s(float d) {
    return fmaf(N2S, __builtin_amdgcn_rcpf(exp2_nat(d) + 1.f), SCL);
}

// lane l + lane l^32 on VALU (R5-proven asm).
__device__ inline float xor32_add(float p) {
    float c = p;
    asm("v_permlane32_swap_b32 %0, %1" : "+v"(c), "+v"(p));
    return p + c;
}

// lane l + lane l^16 via compiler-modeled builtin (R13-proven bit-exact).
__device__ inline float xor16_add(float p) {
#if __has_builtin(__builtin_amdgcn_permlane16_swap)
    uint2v r = __builtin_amdgcn_permlane16_swap(__float_as_uint(p),
                                                __float_as_uint(p),
                                                false, false);
    return __uint_as_float(r[0]) + __uint_as_float(r[1]);
#else
    return p + __shfl_xor(p, 16);
#endif
}

// Barrier waiting only on LDS ops (R9/R10-proven >= neutral).
__device__ inline void lds_barrier() {
    asm volatile("s_waitcnt lgkmcnt(0)\n\ts_barrier" ::: "memory");
}

#define TS 1000
#define ROWU 33            // uint4 granules per h1 row (512B + 16B pad)
#define P2ROW 208          // part2 row bytes: 8x16 hi quads + 8x8 lo pairs + pad

// R15 = R13 + scale-fold (kills the per-tanh input mul; W2/W3 frags untouched)
//           + branchless stage-A fragment build (masks replace divergent ifs).
__global__ __launch_bounds__(512, 4)
void node_ode_kernel(const float* __restrict__ Ig, const float* __restrict__ tg,
                     const float* __restrict__ W1g, const float* __restrict__ b1g,
                     const float* __restrict__ W2g, const float* __restrict__ b2g,
                     const float* __restrict__ W3g, const float* __restrict__ b3g,
                     float* __restrict__ outp)
{
    __shared__ __align__(16) uint4 h1q[16 * ROWU];     // 8448 B
    __shared__ __align__(16) char part2[16 * P2ROW];   // 3328 B
    __shared__ float dtss[TS - 1];                     // 3996 B

    const int tid  = threadIdx.x;
    const int lane = tid & 63;
    const int wv   = tid >> 6;       // 0..7
    const int nb   = lane & 15;      // batch row in tile
    const int g4   = lane >> 4;      // 0..3
    const int bb0  = blockIdx.x * 16;

    const int wbase = nb * ROWU + wv * 4 + g4;   // stage-A write slot (uint4)
    const int rbase = nb * ROWU + g4;            // stage-B read base (+ks*4)
    char* const prow = part2 + nb * P2ROW;

    // per-lane masks for the branchless stage-A B-fragment build
    const unsigned int m0 = (g4 < 2)  ? 0xFFFFFFFFu : 0u;
    const unsigned int m1 = (g4 == 0) ? 0xFFFFFFFFu : ((g4 == 1) ? 0x0000FFFFu : 0u);
    const unsigned int m2 = (g4 == 0) ? 0xFFFFFFFFu : 0u;
    const unsigned int mb = (g4 == 0) ? 0x00003f80u : 0u;   // bf16 1.0 in k=6

    for (int i = tid; i < TS - 1; i += 512) dtss[i] = tg[i + 1] - tg[i];

    const float b30 = b3g[0], b31 = b3g[1], b32 = b3g[2];

    // b2 (SCALE-folded in fp32 regs): acc0 ch = wv*32+4g4+r, acc1 = +16
    float4 b2r0, b2r1;
    {
        float4 t0 = *(const float4*)&b2g[wv * 32 + g4 * 4];
        float4 t1 = *(const float4*)&b2g[wv * 32 + 16 + g4 * 4];
        b2r0 = make_float4(t0.x * SCL, t0.y * SCL, t0.z * SCL, t0.w * SCL);
        b2r1 = make_float4(t1.x * SCL, t1.y * SCL, t1.z * SCL, t1.w * SCL);
    }

    // ---- per-thread RK4 state ----
    float y00 = Ig[(bb0 + nb) * 3 + 0];
    float y01 = Ig[(bb0 + nb) * 3 + 1];
    float y02 = Ig[(bb0 + nb) * 3 + 2];
    if (tid < 16) {
        size_t o = (size_t)(bb0 + tid) * (TS * 3);
        outp[o + 0] = y00; outp[o + 1] = y01; outp[o + 2] = y02;
    }

    // ---- W2 persistent A-frags (unpermuted cols, NO re-rounding — R8 VERBATIM) ----
    bf16x8 w2f[2][8];
    {
        const int ncb = wv * 32 + nb;
        #pragma unroll
        for (int mt = 0; mt < 2; ++mt) {
            #pragma unroll
            for (int ks = 0; ks < 8; ++ks) {
                FU f;
                #pragma unroll
                for (int jj = 0; jj < 4; ++jj) {
                    int k0 = ks * 32 + g4 * 8 + jj * 2;
                    f.u[jj] = cvt_pk(W2g[(size_t)k0 * 256 + ncb + mt * 16],
                                     W2g[(size_t)(k0 + 1) * 256 + ncb + mt * 16]);
                }
                w2f[mt][ks] = f.v;
            }
        }
    }

    // ---- W1 persistent A-frags: SCALE folded BEFORE the split (hi+lo absorbs
    //      the scale exactly — no precision loss), permuted cols (R8 layout) ----
    bf16x8 w1a[2];
    {
        const int colb = wv * 32 + ((nb >> 2) << 3) + (nb & 3);
        #pragma unroll
        for (int mt = 0; mt < 2; ++mt) {
            const int col = colb + mt * 4;
            float w0 = W1g[col] * SCL, w1 = W1g[256 + col] * SCL,
                  w2 = W1g[512 + col] * SCL, bb = b1g[col] * SCL;
            FU f;
            if (g4 == 0) {
                f.u[0] = cvt_pk(w0, w1);
                f.u[1] = cvt_pk(w2, w0);
                f.u[2] = cvt_pk(w1, w2);
                f.u[3] = cvt_pk(bb, 0.f);
            } else if (g4 == 1) {
                unsigned int p01 = cvt_pk(w0, w1);
                unsigned int p2x = cvt_pk(w2, 0.f);
                float w0l = w0 - __uint_as_float(p01 << 16);
                float w1l = w1 - __uint_as_float(p01 & 0xFFFF0000u);
                float w2l = w2 - __uint_as_float(p2x << 16);
                f.u[0] = cvt_pk(w0l, w1l);
                f.u[1] = cvt_pk(w2l, 0.f);
                f.u[2] = 0u; f.u[3] = 0u;
            } else {
                f.u[0] = f.u[1] = f.u[2] = f.u[3] = 0u;
            }
            w1a[mt] = f.v;
        }
    }

    // ---- W3 persistent A-frag (R8 VERBATIM): rows 0-2 hi, 3-5 lo; unscaled ----
    bf16x8 w3a;
    {
        FU f; f.u[0] = f.u[1] = f.u[2] = f.u[3] = 0u;
        if (nb < 6) {
            const int d = (nb < 3) ? nb : nb - 3;
            float w[8];
            #pragma unroll
            for (int j = 0; j < 8; ++j) {
                int ch = (j < 4) ? (wv * 32 + 4 * g4 + j)
                                 : (wv * 32 + 16 + 4 * g4 + (j - 4));
                w[j] = W3g[ch * 3 + d];
            }
            #pragma unroll
            for (int p = 0; p < 4; ++p) {
                unsigned int hp = cvt_pk(w[2 * p], w[2 * p + 1]);
                if (nb < 3) {
                    f.u[p] = hp;
                } else {
                    float l0 = w[2 * p]     - __uint_as_float(hp << 16);
                    float l1 = w[2 * p + 1] - __uint_as_float(hp & 0xFFFF0000u);
                    f.u[p] = cvt_pk(l0, l1);
                }
            }
        }
        w3a = f.v;
    }
    __syncthreads();   // init barrier: full drain, once

    auto EVAL = [&](float ycx, float ycy, float ycz,
                    float& kkx, float& kky, float& kkz) {
        // stage A: split-precision W1 mfma (pre-scaled); branchless frag build;
        //          h1 stored as bf16(S*tanh) via tanh_pre_s — no input mul.
        {
            unsigned int u01  = cvt_pk(ycx, ycy);
            float yl0 = ycx - __uint_as_float(u01 << 16);
            float yl1 = ycy - __uint_as_float(u01 & 0xFFFF0000u);
            unsigned int u2l0 = cvt_pk(ycz, yl0);
            float yl2 = ycz - __uint_as_float(u2l0 << 16);
            unsigned int ull  = cvt_pk(yl1, yl2);
            FU bf;
            bf.u[0] = u01  & m0;
            bf.u[1] = u2l0 & m1;
            bf.u[2] = ull  & m2;
            bf.u[3] = mb;
            f32x4 dA = {0.f, 0.f, 0.f, 0.f};
            f32x4 dB = {0.f, 0.f, 0.f, 0.f};
            dA = __builtin_amdgcn_mfma_f32_16x16x32_bf16(w1a[0], bf.v, dA, 0, 0, 0);
            dB = __builtin_amdgcn_mfma_f32_16x16x32_bf16(w1a[1], bf.v, dB, 0, 0, 0);
            uint4 wq;
            wq.x = cvt_pk(tanh_pre_s(dA[0]), tanh_pre_s(dA[1]));
            wq.y = cvt_pk(tanh_pre_s(dA[2]), tanh_pre_s(dA[3]));
            wq.z = cvt_pk(tanh_pre_s(dB[0]), tanh_pre_s(dB[1]));
            wq.w = cvt_pk(tanh_pre_s(dB[2]), tanh_pre_s(dB[3]));
            h1q[wbase] = wq;
        }
        lds_barrier();

        // stage B: 16 W2 mfma (inputs carry the scale) + 8 tanh_pre + pack
        //          + 1 W3 mfma + partial write
        {
            f32x4 acc0 = {b2r0.x, b2r0.y, b2r0.z, b2r0.w};
            f32x4 acc1 = {b2r1.x, b2r1.y, b2r1.z, b2r1.w};
            #pragma unroll
            for (int ks = 0; ks < 8; ++ks) {
                FU tm; tm.q = h1q[rbase + ks * 4];
                acc0 = __builtin_amdgcn_mfma_f32_16x16x32_bf16(w2f[0][ks], tm.v, acc0, 0, 0, 0);
                acc1 = __builtin_amdgcn_mfma_f32_16x16x32_bf16(w2f[1][ks], tm.v, acc1, 0, 0, 0);
            }
            FU pb;
            pb.u[0] = cvt_pk(tanh_pre(acc0[0]), tanh_pre(acc0[1]));
            pb.u[1] = cvt_pk(tanh_pre(acc0[2]), tanh_pre(acc0[3]));
            pb.u[2] = cvt_pk(tanh_pre(acc1[0]), tanh_pre(acc1[1]));
            pb.u[3] = cvt_pk(tanh_pre(acc1[2]), tanh_pre(acc1[3]));
            f32x4 pd = {0.f, 0.f, 0.f, 0.f};
            pd = __builtin_amdgcn_mfma_f32_16x16x32_bf16(w3a, pb.v, pd, 0, 0, 0);
            if (g4 == 0)
                *(float4*)(prow + wv * 16) = make_float4(pd[0], pd[1], pd[2], pd[3]);
            else if (g4 == 1)
                *(float2*)(prow + 128 + wv * 8) = make_float2(pd[0], pd[1]);
        }
        lds_barrier();

        // combine: 3 reads distributed over g4 + xor16 (builtin) + xor32 (asm)
        {
            float4 q1 = *(const float4*)(prow + g4 * 16);
            float4 q2 = *(const float4*)(prow + 64 + g4 * 16);
            float4 q3 = *(const float4*)(prow + 128 + g4 * 16);
            float k0 = (q1.x + q2.x) + (q1.w + q2.w);
            float k1 = (q1.y + q2.y) + (q3.x + q3.z);
            float k2 = (q1.z + q2.z) + (q3.y + q3.w);
            k0 = xor16_add(k0); k1 = xor16_add(k1); k2 = xor16_add(k2);
            kkx = xor32_add(k0) + b30;
            kky = xor32_add(k1) + b31;
            kkz = xor32_add(k2) + b32;
        }
    };

    for (int t = 0; t < TS - 1; ++t) {
        const float dtc = dtss[t];
        const float hh = 0.5f * dtc;
        float k1x, k1y, k1z, k2x, k2y, k2z, k3x, k3y, k3z, k4x, k4y, k4z;
        EVAL(y00, y01, y02, k1x, k1y, k1z);
        EVAL(fmaf(hh, k1x, y00), fmaf(hh, k1y, y01), fmaf(hh, k1z, y02),
             k2x, k2y, k2z);
        EVAL(fmaf(hh, k2x, y00), fmaf(hh, k2y, y01), fmaf(hh, k2z, y02),
             k3x, k3y, k3z);
        EVAL(fmaf(dtc, k3x, y00), fmaf(dtc, k3y, y01), fmaf(dtc, k3z, y02),
             k4x, k4y, k4z);
        const float s = dtc * (1.f / 6.f);
        y00 = fmaf(s, (k1x + k4x) + 2.f * (k2x + k3x), y00);
        y01 = fmaf(s, (k1y + k4y) + 2.f * (k2y + k3y), y01);
        y02 = fmaf(s, (k1z + k4z) + 2.f * (k2z + k3z), y02);
        // rotate the storing wave so outstanding global stores spread across waves
        if ((wv == (t & 7)) && lane < 16) {
            size_t o = (size_t)(bb0 + nb) * (TS * 3) + (size_t)(t + 1) * 3;
            outp[o + 0] = y00; outp[o + 1] = y01; outp[o + 2] = y02;
        }
    }
}

extern "C" void kernel_launch(void* const* d_in, const int* in_sizes, int n_in,
                              void* d_out, int out_size, void* d_ws, size_t ws_size,
                              hipStream_t stream) {
    (void)in_sizes; (void)n_in; (void)d_ws; (void)ws_size; (void)out_size;
    const float* Ig  = (const float*)d_in[0];
    const float* tg  = (const float*)d_in[1];
    const float* W1g = (const float*)d_in[2];
    const float* b1g = (const float*)d_in[3];
    const float* W2g = (const float*)d_in[4];
    const float* b2g = (const float*)d_in[5];
    const float* W3g = (const float*)d_in[6];
    const float* b3g = (const float*)d_in[7];
    float* outp = (float*)d_out;

    dim3 grid(512), block(512);
    hipLaunchKernelGGL(node_ode_kernel, grid, block, 0, stream,
                       Ig, tg, W1g, b1g, W2g, b2g, W3g, b3g, outp);
}